// Round 5
// baseline (309.490 us; speedup 1.0000x reference)
//
#include <hip/hip_runtime.h>
#include <hip/hip_bf16.h>
#include <math.h>

#define N_POS 4096
#define C_DIM 528
#define NHEAD 8
#define HDIM  66
#define KNN   32
#define CQKV  1584
#define KP    544      // 528 padded to 17*32
#define NP1   1664     // 1584 padded to 13*128
#define NP2   640      // 528 padded to 5*128

typedef __attribute__((ext_vector_type(8))) short short8;
typedef __attribute__((ext_vector_type(4))) float f32x4;
typedef __hip_bfloat16 bf16;

typedef const __attribute__((address_space(1))) void* gas1;
typedef __attribute__((address_space(3))) void* las3;

// ---------------------------------------------------------------------------
// Fused f32 -> bf16 conversion with zero padding to [Npad][KP] row-major.
// ---------------------------------------------------------------------------
__global__ __launch_bounds__(256) void convpad3_kernel(
    const float* __restrict__ x, const float* __restrict__ wq,
    const float* __restrict__ wp,
    bf16* __restrict__ xb, bf16* __restrict__ wqb, bf16* __restrict__ wpb)
{
    int b = blockIdx.x;
    const float* src; bf16* dst; int Nr;
    if (b < N_POS)            { src = x;  dst = xb;  Nr = N_POS; }
    else if (b < N_POS + NP1) { b -= N_POS; src = wq; dst = wqb; Nr = CQKV; }
    else                      { b -= N_POS + NP1; src = wp; dst = wpb; Nr = C_DIM; }
    for (int c = threadIdx.x; c < KP; c += 256) {
        float v = (b < Nr && c < C_DIM) ? src[(size_t)b * C_DIM + c] : 0.0f;
        dst[(size_t)b * KP + c] = __float2bfloat16(v);
    }
}

// ---------------------------------------------------------------------------
// bf16 MFMA GEMM, 64x64 tile for 4x grid parallelism (1664/640 blocks ->
// TLP hides staging latency; weights+activations are L2-resident so the
// lower AI is absorbed by L2). 4 waves (2x2), each 32x32 out = 2x2 frags of
// 16x16x32. 2-phase global_load_lds double-buffer, source pre-swizzle
// col16=(lane&3)^((r>>1)&3), matching XOR on read (2 lanes/bank, free).
// ---------------------------------------------------------------------------
__global__ __launch_bounds__(256) void gemm_mfma_kernel(
    const bf16* __restrict__ A, const bf16* __restrict__ B,
    const float* __restrict__ bias, float* __restrict__ C,
    int Nreal, int ldc)
{
    __shared__ bf16 As[2][64 * 32];   // 2 x 4 KB
    __shared__ bf16 Bs[2][64 * 32];   // 2 x 4 KB

    const int tid  = threadIdx.x;
    const int lane = tid & 63;
    const int wid  = tid >> 6;
    const int bm = blockIdx.y * 64;
    const int bn = blockIdx.x * 64;

    // staging: wave wid stages A rows [16w,16w+16) and B rows [16w,16w+16)
    const int r   = (wid << 4) + (lane >> 2);
    const int csw = ((lane & 3) ^ ((r >> 1) & 3)) << 3;

    const bf16* Ag = A + (size_t)(bm + r) * KP + csw;
    const bf16* Bg = B + (size_t)(bn + r) * KP + csw;

    bf16* as0 = &As[0][0] + (wid << 4) * 32;   // wave-uniform LDS bases (buf0)
    bf16* bs0 = &Bs[0][0] + (wid << 4) * 32;
    const int BUF = 64 * 32;

    // fragment read coords: wave (wm,wn) covers 32x32
    const int wm = (wid >> 1) * 32;
    const int wn = (wid & 1) * 32;
    const int arow = wm + (lane & 15);
    const int brow = wn + (lane & 15);
    const int seg  = lane >> 4;
    const int aoff = (seg ^ ((arow >> 1) & 3)) << 3;
    const int boff = (seg ^ ((brow >> 1) & 3)) << 3;

    f32x4 acc[2][2];
    #pragma unroll
    for (int i = 0; i < 2; ++i)
        #pragma unroll
        for (int j = 0; j < 2; ++j)
            acc[i][j] = (f32x4){0.f, 0.f, 0.f, 0.f};

    // prologue: stage k=0 into buf0
    __builtin_amdgcn_global_load_lds((gas1)(Ag), (las3)(as0), 16, 0, 0);
    __builtin_amdgcn_global_load_lds((gas1)(Bg), (las3)(bs0), 16, 0, 0);
    __syncthreads();

    int cur = 0;
    for (int k0 = 0; k0 < KP; k0 += 32) {
        if (k0 + 32 < KP) {
            const int nb = cur ^ 1;
            __builtin_amdgcn_global_load_lds((gas1)(Ag + k0 + 32), (las3)(as0 + nb * BUF), 16, 0, 0);
            __builtin_amdgcn_global_load_lds((gas1)(Bg + k0 + 32), (las3)(bs0 + nb * BUF), 16, 0, 0);
        }

        const bf16* ab = &As[cur][0];
        const bf16* bb = &Bs[cur][0];
        short8 af[2], bfr[2];
        #pragma unroll
        for (int f = 0; f < 2; ++f)
            af[f] = *(const short8*)&ab[(arow + f * 16) * 32 + aoff];
        #pragma unroll
        for (int f = 0; f < 2; ++f)
            bfr[f] = *(const short8*)&bb[(brow + f * 16) * 32 + boff];

        #pragma unroll
        for (int i = 0; i < 2; ++i)
            #pragma unroll
            for (int j = 0; j < 2; ++j)
                acc[i][j] = __builtin_amdgcn_mfma_f32_16x16x32_bf16(
                    af[i], bfr[j], acc[i][j], 0, 0, 0);

        __syncthreads();
        cur ^= 1;
    }

    // epilogue: C/D layout col=lane&15, row=(lane>>4)*4+reg
    #pragma unroll
    for (int i = 0; i < 2; ++i) {
        const int row = bm + wm + i * 16 + (lane >> 4) * 4;
        #pragma unroll
        for (int j = 0; j < 2; ++j) {
            const int col = bn + wn + j * 16 + (lane & 15);
            if (col < Nreal) {
                const float bv = bias[col];
                #pragma unroll
                for (int rr = 0; rr < 4; ++rr)
                    C[(size_t)(row + rr) * ldc + col] = acc[i][j][rr] + bv;
            }
        }
    }
}

// ---------------------------------------------------------------------------
// Zero-LDS streaming attention: one WAVE per (h,n). knn_kv has no reuse,
// so no staging: 33 lanes stream k/v rows as float2 (264 B dense), V kept
// in registers (single pass, no line re-fetch), in-wave shuffle softmax.
// out: [N_POS][KP] bf16.
// ---------------------------------------------------------------------------
__global__ __launch_bounds__(256) void attn_kernel(
    const float* __restrict__ qkv, const float* __restrict__ knn,
    bf16* __restrict__ out)
{
    const float scaling = 0.12309149097933272f;  // 66^-0.5

    const int gw   = (blockIdx.x << 2) + (threadIdx.x >> 6);  // (h,n) pair id
    const int lane = threadIdx.x & 63;
    const int h = gw >> 12;
    const int n = gw & 4095;
    const bool act = lane < 33;

    // self q,k,v: 33 lanes x float2 = 66 elems
    const float* qp = qkv + (size_t)n * CQKV + h * HDIM;
    float2 q2 = {0.f, 0.f}, k2 = {0.f, 0.f}, v2 = {0.f, 0.f};
    if (act) {
        q2 = *(const float2*)(qp + 2 * lane);
        k2 = *(const float2*)(qp + C_DIM + 2 * lane);
        v2 = *(const float2*)(qp + 2 * C_DIM + 2 * lane);
    }

    // l2 norms (full-wave reduce; idle lanes contribute 0)
    float sq = q2.x * q2.x + q2.y * q2.y;
    float sk = k2.x * k2.x + k2.y * k2.y;
    #pragma unroll
    for (int off = 32; off; off >>= 1) {
        sq += __shfl_xor(sq, off);
        sk += __shfl_xor(sk, off);
    }
    const float iq = 1.0f / fmaxf(sqrtf(sq), 1e-12f);
    const float ik = 1.0f / fmaxf(sqrtf(sk), 1e-12f);
    q2.x *= iq; q2.y *= iq;
    k2.x *= ik; k2.y *= ik;

    // stream 32 knn (k,v) rows; keep v in regs; dot -> p[lane==j]
    const float* kb = knn + (size_t)gw * (KNN * 2 * HDIM);
    float p = -3.4e38f;
    float2 vr[KNN + 1];
    #pragma unroll
    for (int j = 0; j < KNN; ++j) {
        float2 kj = {0.f, 0.f}, vj = {0.f, 0.f};
        if (act) {
            kj = *(const float2*)(kb + j * 132 + 2 * lane);
            vj = *(const float2*)(kb + j * 132 + HDIM + 2 * lane);
        }
        vr[j] = vj;
        float d = q2.x * kj.x + q2.y * kj.y;
        #pragma unroll
        for (int off = 32; off; off >>= 1) d += __shfl_xor(d, off);
        if (lane == j) p = d * scaling;
    }
    vr[KNN] = v2;
    {
        float d = q2.x * k2.x + q2.y * k2.y;
        #pragma unroll
        for (int off = 32; off; off >>= 1) d += __shfl_xor(d, off);
        if (lane == KNN) p = d * scaling;
    }

    // softmax over lanes 0..32 (others hold -inf -> exp 0)
    float m = p;
    #pragma unroll
    for (int off = 32; off; off >>= 1) m = fmaxf(m, __shfl_xor(m, off));
    float e = expf(p - m);
    float s = e;
    #pragma unroll
    for (int off = 32; off; off >>= 1) s += __shfl_xor(s, off);
    const float pr = e / s;

    // PV: broadcast p_j, accumulate on the in-register V rows
    float2 acc = {0.f, 0.f};
    #pragma unroll
    for (int j = 0; j <= KNN; ++j) {
        const float pj = __shfl(pr, j);
        acc.x += pj * vr[j].x;
        acc.y += pj * vr[j].y;
    }

    if (act) {
        bf16* op = out + (size_t)n * KP + h * HDIM + 2 * lane;
        __hip_bfloat162 o2;
        o2.x = __float2bfloat16(acc.x);
        o2.y = __float2bfloat16(acc.y);
        *(__hip_bfloat162*)op = o2;
    }
    if (h == 0 && lane < KP - C_DIM)   // zero the K-pad columns once per row
        out[(size_t)n * KP + C_DIM + lane] = __float2bfloat16(0.0f);
}

extern "C" void kernel_launch(void* const* d_in, const int* in_sizes, int n_in,
                              void* d_out, int out_size, void* d_ws, size_t ws_size,
                              hipStream_t stream)
{
    const float* x      = (const float*)d_in[0];
    const float* knn_kv = (const float*)d_in[1];
    const float* w_qkv  = (const float*)d_in[2];
    const float* b_qkv  = (const float*)d_in[3];
    const float* w_proj = (const float*)d_in[4];
    const float* b_proj = (const float*)d_in[5];
    float* out = (float*)d_out;

    char* ws = (char*)d_ws;
    float* qkv = (float*)ws;                                  // 4096*1584 f32 = 25,952,256 B
    bf16*  xb  = (bf16*)(ws + 25952256);                      // 4096*544*2 = 4,456,448 B
    bf16*  wqb = (bf16*)(ws + 25952256 + 4456448);            // 1664*544*2 = 1,810,432 B
    bf16*  wpb = (bf16*)(ws + 25952256 + 4456448 + 1810432);  // 640*544*2  =   696,320 B
    bf16*  ab  = (bf16*)(ws + 25952256 + 4456448 + 1810432 + 696320);  // 4096*544*2

    convpad3_kernel<<<N_POS + NP1 + NP2, 256, 0, stream>>>(x, w_qkv, w_proj, xb, wqb, wpb);

    gemm_mfma_kernel<<<dim3(NP1 / 64, N_POS / 64), 256, 0, stream>>>(
        xb, wqb, b_qkv, qkv, CQKV, CQKV);

    attn_kernel<<<dim3(NHEAD * N_POS / 4), 256, 0, stream>>>(qkv, knn_kv, ab);

    gemm_mfma_kernel<<<dim3(NP2 / 64, N_POS / 64), 256, 0, stream>>>(
        ab, wpb, b_proj, out, C_DIM, C_DIM);
}

// Round 6
// 170.971 us; speedup vs baseline: 1.8102x; 1.8102x over previous
//
#include <hip/hip_runtime.h>
#include <hip/hip_bf16.h>
#include <math.h>

#define N_POS 4096
#define C_DIM 528
#define NHEAD 8
#define HDIM  66
#define KNN   32
#define CQKV  1584
#define KP    544      // 528 padded to 17*32
#define NP1   1664     // 1584 padded to 13*128
#define NP2   640      // 528 padded to 5*128

typedef __attribute__((ext_vector_type(8))) short short8;
typedef __attribute__((ext_vector_type(4))) float f32x4;
typedef __hip_bfloat16 bf16;

// ---------------------------------------------------------------------------
// Fused f32 -> bf16 conversion with zero padding to [Npad][KP] row-major.
// ---------------------------------------------------------------------------
__global__ __launch_bounds__(256) void convpad3_kernel(
    const float* __restrict__ x, const float* __restrict__ wq,
    const float* __restrict__ wp,
    bf16* __restrict__ xb, bf16* __restrict__ wqb, bf16* __restrict__ wpb)
{
    int b = blockIdx.x;
    const float* src; bf16* dst; int Nr;
    if (b < N_POS)            { src = x;  dst = xb;  Nr = N_POS; }
    else if (b < N_POS + NP1) { b -= N_POS; src = wq; dst = wqb; Nr = CQKV; }
    else                      { b -= N_POS + NP1; src = wp; dst = wpb; Nr = C_DIM; }
    for (int c = threadIdx.x; c < KP; c += 256) {
        float v = (b < Nr && c < C_DIM) ? src[(size_t)b * C_DIM + c] : 0.0f;
        dst[(size_t)b * KP + c] = __float2bfloat16(v);
    }
}

// ---------------------------------------------------------------------------
// bf16 MFMA GEMM (R2 winner, verbatim): reg-staged, 128x128 tile, BK=32,
// 4 waves (2x2), 16x16x32 MFMA, 4x4 frags/wave, 16B-slot XOR swizzle.
// ---------------------------------------------------------------------------
__global__ __launch_bounds__(256) void gemm_mfma_kernel(
    const bf16* __restrict__ A, const bf16* __restrict__ B,
    const float* __restrict__ bias, float* __restrict__ C,
    int Nreal, int ldc)
{
    __shared__ short8 As[512];   // 128 rows x 4 x 16B = 8 KB
    __shared__ short8 Bs[512];

    const int tid  = threadIdx.x;
    const int lane = tid & 63;
    const int wid  = tid >> 6;
    const int bm = blockIdx.y * 128;
    const int bn = blockIdx.x * 128;

    const int r0 = tid >> 2;
    const int c0 = tid & 3;
    const bf16* Ag = A + (size_t)(bm + r0) * KP + c0 * 8;
    const bf16* Bg = B + (size_t)(bn + r0) * KP + c0 * 8;
    const size_t roff = (size_t)64 * KP;

    short8 a0 = *(const short8*)(Ag);
    short8 a1 = *(const short8*)(Ag + roff);
    short8 b0 = *(const short8*)(Bg);
    short8 b1 = *(const short8*)(Bg + roff);

    const int w0 = r0 * 4 + (c0 ^ (r0 & 3));
    const int w1 = w0 + 256;

    const int wm = (wid >> 1) * 64;
    const int wn = (wid & 1) * 64;
    const int arow = wm + (lane & 15);
    const int brow = wn + (lane & 15);
    const int apc  = lane >> 4;
    const int aslot = arow * 4 + (apc ^ (arow & 3));
    const int bslot = brow * 4 + (apc ^ (brow & 3));

    f32x4 acc[4][4];
    #pragma unroll
    for (int i = 0; i < 4; ++i)
        #pragma unroll
        for (int j = 0; j < 4; ++j)
            acc[i][j] = (f32x4){0.f, 0.f, 0.f, 0.f};

    for (int k0 = 0;; k0 += 32) {
        As[w0] = a0; As[w1] = a1;
        Bs[w0] = b0; Bs[w1] = b1;
        __syncthreads();
        if (k0 + 32 < KP) {
            const bf16* An = Ag + (k0 + 32);
            const bf16* Bn = Bg + (k0 + 32);
            a0 = *(const short8*)(An);
            a1 = *(const short8*)(An + roff);
            b0 = *(const short8*)(Bn);
            b1 = *(const short8*)(Bn + roff);
        }
        short8 af[4], bfr[4];
        #pragma unroll
        for (int f = 0; f < 4; ++f) af[f]  = As[aslot + f * 64];
        #pragma unroll
        for (int f = 0; f < 4; ++f) bfr[f] = Bs[bslot + f * 64];
        #pragma unroll
        for (int i = 0; i < 4; ++i)
            #pragma unroll
            for (int j = 0; j < 4; ++j)
                acc[i][j] = __builtin_amdgcn_mfma_f32_16x16x32_bf16(
                    af[i], bfr[j], acc[i][j], 0, 0, 0);
        if (k0 + 32 >= KP) break;
        __syncthreads();
    }

    #pragma unroll
    for (int i = 0; i < 4; ++i) {
        const int row = bm + wm + i * 16 + (lane >> 4) * 4;
        #pragma unroll
        for (int j = 0; j < 4; ++j) {
            const int col = bn + wn + j * 16 + (lane & 15);
            if (col < Nreal) {
                const float bv = bias[col];
                #pragma unroll
                for (int r = 0; r < 4; ++r)
                    C[(size_t)(row + r) * ldc + col] = acc[i][j][r] + bv;
            }
        }
    }
}

// ---------------------------------------------------------------------------
// Streaming attention: one block per TWO (h,n) pairs. All global loads
// issued before LDS writes (one latency for 34 KB). Normalization deferred
// to logits (no q/k rewrite). Per 2-wave team: wave A = 32 knn dots
// (2 lanes/key), wave B = norms + self-dot concurrently. 3 barriers.
// out: [N_POS][KP] bf16.
// ---------------------------------------------------------------------------
__global__ __launch_bounds__(256) void attn_kernel(
    const float* __restrict__ qkv, const float* __restrict__ knn,
    bf16* __restrict__ out)
{
    const float scaling = 0.12309149097933272f;  // 66^-0.5

    const int bid = blockIdx.x;
    const int tid = threadIdx.x;
    const int g0  = bid << 1;                 // first pair id
    const int h   = g0 >> 12;                 // same h for both pairs
    const int n0  = g0 & 4095;
    const int n1  = n0 + 1;

    __shared__ float s_knn[2][KNN * 132];     // 2 x 16.5 KB
    __shared__ float s_qkv[2][3 * HDIM];      // q,k,v rows (raw)
    __shared__ float s_dot[2][KNN + 1];
    __shared__ float s_sc[2][2];              // {iq*scaling, self_logit}

    // ---- stage: issue ALL global loads first, then LDS writes ----
    const float4* kb0 = (const float4*)(knn + (size_t)g0 * (KNN * 132));
    const float4* kb1 = kb0 + KNN * 33;       // next pair, contiguous
    float4 r0[4], r1[4];
    float4 e0 = {0.f, 0.f, 0.f, 0.f}, e1 = {0.f, 0.f, 0.f, 0.f};
    #pragma unroll
    for (int i = 0; i < 4; ++i) r0[i] = kb0[tid + 256 * i];
    if (tid < 32) e0 = kb0[1024 + tid];
    #pragma unroll
    for (int i = 0; i < 4; ++i) r1[i] = kb1[tid + 256 * i];
    if (tid < 32) e1 = kb1[1024 + tid];

    const float* qp0 = qkv + (size_t)n0 * CQKV + h * HDIM;
    const float* qp1 = qp0 + CQKV;
    float qv0 = 0.f, qv1 = 0.f;
    int part = tid / HDIM, d66 = tid - part * HDIM;
    if (tid < 3 * HDIM) {
        qv0 = qp0[part * C_DIM + d66];
        qv1 = qp1[part * C_DIM + d66];
    }

    float4* s40 = (float4*)s_knn[0];
    float4* s41 = (float4*)s_knn[1];
    #pragma unroll
    for (int i = 0; i < 4; ++i) s40[tid + 256 * i] = r0[i];
    if (tid < 32) s40[1024 + tid] = e0;
    #pragma unroll
    for (int i = 0; i < 4; ++i) s41[tid + 256 * i] = r1[i];
    if (tid < 32) s41[1024 + tid] = e1;
    if (tid < 3 * HDIM) {
        s_qkv[0][tid] = qv0;
        s_qkv[1][tid] = qv1;
    }
    __syncthreads();

    const int team  = tid >> 7;               // 0/1 -> pair
    const int ttid  = tid & 127;
    const int twave = ttid >> 6;
    const int lane  = tid & 63;
    const float* kK = s_knn[team];
    const float* Q  = &s_qkv[team][0];
    const float* KS = &s_qkv[team][HDIM];

    if (twave == 0) {
        // 32 knn dots with RAW q: 2 lanes per key
        const int j = lane >> 1, l2 = lane & 1;
        const float* kr = kK + j * 132;
        float p = 0.f;
        #pragma unroll
        for (int d = 0; d < HDIM / 2; ++d) p += Q[2 * d + l2] * kr[2 * d + l2];
        p += __shfl_xor(p, 1);
        if (l2 == 0) s_dot[team][j] = p;
    } else {
        // norms of q,k + self-dot, concurrently
        float aq, ak, qk;
        {
            float qd = Q[lane], kd = KS[lane];
            aq = qd * qd; ak = kd * kd; qk = qd * kd;
            if (lane < 2) {
                float q2 = Q[64 + lane], k2 = KS[64 + lane];
                aq += q2 * q2; ak += k2 * k2; qk += q2 * k2;
            }
        }
        #pragma unroll
        for (int off = 32; off; off >>= 1) {
            aq += __shfl_xor(aq, off);
            ak += __shfl_xor(ak, off);
            qk += __shfl_xor(qk, off);
        }
        if (lane == 0) {
            const float iq = 1.0f / fmaxf(sqrtf(aq), 1e-12f);
            const float ik = 1.0f / fmaxf(sqrtf(ak), 1e-12f);
            s_sc[team][0] = iq * scaling;
            s_sc[team][1] = qk * iq * ik * scaling;
        }
    }
    __syncthreads();

    // softmax over 33 (team wave 0)
    if (twave == 0) {
        float x = -3.4e38f;
        if (lane < 32)       x = s_dot[team][lane] * s_sc[team][0];
        else if (lane == 32) x = s_sc[team][1];
        float m = x;
        #pragma unroll
        for (int off = 32; off; off >>= 1) m = fmaxf(m, __shfl_xor(m, off));
        float e = (lane < 33) ? expf(x - m) : 0.f;
        float s = e;
        #pragma unroll
        for (int off = 32; off; off >>= 1) s += __shfl_xor(s, off);
        if (lane < 33) s_dot[team][lane] = e / s;
    }
    __syncthreads();

    // PV: thread d of team sums 33 keys
    if (ttid < HDIM) {
        const int d = ttid;
        float acc = s_dot[team][KNN] * s_qkv[team][2 * HDIM + d];
        #pragma unroll 8
        for (int j = 0; j < KNN; ++j)
            acc += s_dot[team][j] * kK[j * 132 + HDIM + d];
        const int n = team ? n1 : n0;
        out[(size_t)n * KP + h * HDIM + d] = __float2bfloat16(acc);
    }
    if (h == 0) {   // zero K-pad columns (cols 528..543) for both rows
        if (tid < 16)
            out[(size_t)n0 * KP + C_DIM + tid] = __float2bfloat16(0.f);
        else if (tid < 32)
            out[(size_t)n1 * KP + C_DIM + (tid - 16)] = __float2bfloat16(0.f);
    }
}

extern "C" void kernel_launch(void* const* d_in, const int* in_sizes, int n_in,
                              void* d_out, int out_size, void* d_ws, size_t ws_size,
                              hipStream_t stream)
{
    const float* x      = (const float*)d_in[0];
    const float* knn_kv = (const float*)d_in[1];
    const float* w_qkv  = (const float*)d_in[2];
    const float* b_qkv  = (const float*)d_in[3];
    const float* w_proj = (const float*)d_in[4];
    const float* b_proj = (const float*)d_in[5];
    float* out = (float*)d_out;

    char* ws = (char*)d_ws;
    float* qkv = (float*)ws;                                  // 4096*1584 f32 = 25,952,256 B
    bf16*  xb  = (bf16*)(ws + 25952256);                      // 4096*544*2 = 4,456,448 B
    bf16*  wqb = (bf16*)(ws + 25952256 + 4456448);            // 1664*544*2 = 1,810,432 B
    bf16*  wpb = (bf16*)(ws + 25952256 + 4456448 + 1810432);  // 640*544*2  =   696,320 B
    bf16*  ab  = (bf16*)(ws + 25952256 + 4456448 + 1810432 + 696320);  // 4096*544*2

    convpad3_kernel<<<N_POS + NP1 + NP2, 256, 0, stream>>>(x, w_qkv, w_proj, xb, wqb, wpb);

    gemm_mfma_kernel<<<dim3(NP1 / 128, N_POS / 128), 256, 0, stream>>>(
        xb, wqb, b_qkv, qkv, CQKV, CQKV);

    attn_kernel<<<dim3(NHEAD * N_POS / 2), 256, 0, stream>>>(qkv, knn_kv, ab);

    gemm_mfma_kernel<<<dim3(NP2 / 128, N_POS / 128), 256, 0, stream>>>(
        ab, wpb, b_proj, out, C_DIM, C_DIM);
}